// Round 2
// baseline (253.268 us; speedup 1.0000x reference)
//
#include <hip/hip_runtime.h>

#define HW 16384   // 128*128

typedef __attribute__((ext_vector_type(8))) short short8;
typedef __attribute__((ext_vector_type(16))) float floatx16;

__device__ inline unsigned short f2bf(float f) {
    unsigned u = __builtin_bit_cast(unsigned, f);
    u = (u + 0x7FFFu + ((u >> 16) & 1u)) >> 16;   // RNE
    return (unsigned short)u;
}

// pack two fp32 -> bf16x2 by truncation: one v_perm_b32
__device__ inline unsigned pack_bf_trunc(float lo, float hi) {
    return __builtin_amdgcn_perm(__builtin_bit_cast(unsigned, hi),
                                 __builtin_bit_cast(unsigned, lo), 0x07060302u);
}

// ---------------------------------------------------------------------------
// Cast W q/k/v -> bf16 Wb[320][256]: rows 0-31 q, 32-63 k, 64-319 v.
// ---------------------------------------------------------------------------
__global__ __launch_bounds__(256) void castW_kernel(
    const float* __restrict__ Wq, const float* __restrict__ Wk,
    const float* __restrict__ Wv, unsigned short* __restrict__ Wb)
{
    int idx4 = blockIdx.x * 256 + threadIdx.x;
    int e0 = idx4 * 4;
    int row = e0 >> 8, col = e0 & 255;
    const float* src = (row < 32) ? (Wq + row * 256 + col)
                     : (row < 64) ? (Wk + (row - 32) * 256 + col)
                                  : (Wv + (row - 64) * 256 + col);
    float4 v = *(const float4*)src;
    uint2 pk;
    pk.x = f2bf(v.x) | ((unsigned)f2bf(v.y) << 16);
    pk.y = f2bf(v.z) | ((unsigned)f2bf(v.w) << 16);
    *(uint2*)&Wb[e0] = pk;
}

// ---------------------------------------------------------------------------
// Cast + transpose x: [b][c][p] fp32 -> xt[b][p][c] bf16.  64c x 64p tiles.
// ---------------------------------------------------------------------------
__global__ __launch_bounds__(256) void cast_xt_kernel(
    const float* __restrict__ x, unsigned short* __restrict__ xt)
{
    __shared__ unsigned short T[64][66];
    const int tid = threadIdx.x;
    const int p0 = blockIdx.x * 64;
    const int c0 = blockIdx.y * 64;
    const int b  = blockIdx.z;
    #pragma unroll
    for (int i = 0; i < 4; i++) {
        int e = i * 256 + tid;
        int c = e >> 4, seg = e & 15;
        float4 v = *(const float4*)&x[((b * 256 + c0 + c) << 14) + p0 + seg * 4];
        ((unsigned*)&T[c][seg * 4])[0] = f2bf(v.x) | ((unsigned)f2bf(v.y) << 16);
        ((unsigned*)&T[c][seg * 4])[1] = f2bf(v.z) | ((unsigned)f2bf(v.w) << 16);
    }
    __syncthreads();
    #pragma unroll
    for (int i = 0; i < 2; i++) {
        int e = i * 256 + tid;
        int p = e >> 3, cs = e & 7;
        unsigned short t[8];
        #pragma unroll
        for (int j = 0; j < 8; j++) t[j] = T[cs * 8 + j][p];
        uint4 pk;
        pk.x = t[0] | ((unsigned)t[1] << 16);
        pk.y = t[2] | ((unsigned)t[3] << 16);
        pk.z = t[4] | ((unsigned)t[5] << 16);
        pk.w = t[6] | ((unsigned)t[7] << 16);
        *(uint4*)&xt[(((b << 14) + p0 + p) << 8) + c0 + cs * 8] = pk;
    }
}

// ---------------------------------------------------------------------------
// MFMA projection v2: one block per 128-px tile, FULL K=256 panel resident in
// LDS (read xt from HBM exactly once, vs 5x with the old y=5 grid). The 5
// oc-groups (q+k, v0..v3) loop inside the block; W fragments are read direct
// from global (L1/L2-resident, shared by all waves/blocks). 8KB C-staging
// drained in two rounds keeps LDS at ~73KB -> 2 blocks/CU.
// ---------------------------------------------------------------------------
__global__ __launch_bounds__(256, 2) void proj_mfma_kernel(
    const unsigned short* __restrict__ Wb, const unsigned short* __restrict__ xt,
    const float* __restrict__ bq, const float* __restrict__ bk,
    const float* __restrict__ bv,
    unsigned short* __restrict__ qb, unsigned short* __restrict__ kb,
    unsigned short* __restrict__ vb)
{
    __shared__ __align__(16) unsigned short Bs[128 * 256];  // [px][k], 16B chunk c^=(px&7)
    __shared__ __align__(16) unsigned short Cs[32 * 128];   // 8KB epilogue staging
    __shared__ float biasS[320];
    const int tid = threadIdx.x;
    const int p0  = blockIdx.x * 128;
    const int b   = blockIdx.y;
    const int w = tid >> 6, lr = tid & 31, lh = (tid & 63) >> 5;

    if (tid < 64) biasS[tid] = (tid < 32) ? bq[tid] : bk[tid - 32];
    biasS[64 + tid] = bv[tid];

    // stage full xt panel: 128px x 256k bf16 = 64KB, swizzled 16B chunks
    const int bpx = (b << 14) + p0;
    #pragma unroll
    for (int i = 0; i < 16; i++) {
        int e = i * 256 + tid;
        int row = e >> 5, c = e & 31, cp = c ^ (row & 7);
        *(uint4*)&Bs[row * 256 + cp * 8] =
            *(const uint4*)&xt[(bpx + row) * 256 + c * 8];
    }
    __syncthreads();

    floatx16 z16 = {0,0,0,0,0,0,0,0,0,0,0,0,0,0,0,0};
    const int brow = 32 * w + lr;

    for (int ocg = 0; ocg < 5; ocg++) {
        const int oc0 = ocg * 64;
        floatx16 acc[2] = {z16, z16};
        const unsigned short* wrow0 = Wb + (oc0 + lr) * 256 + 8 * lh;
        const unsigned short* wrow1 = Wb + (oc0 + 32 + lr) * 256 + 8 * lh;
        #pragma unroll
        for (int ks = 0; ks < 16; ks++) {
            short8 af0 = *(const short8*)(wrow0 + 16 * ks);
            short8 af1 = *(const short8*)(wrow1 + 16 * ks);
            int cpk = ((2 * ks + lh) ^ (brow & 7)) * 8;
            short8 bfr = *(const short8*)&Bs[brow * 256 + cpk];
            acc[0] = __builtin_amdgcn_mfma_f32_32x32x16_bf16(af0, bfr, acc[0], 0, 0, 0);
            acc[1] = __builtin_amdgcn_mfma_f32_32x32x16_bf16(af1, bfr, acc[1], 0, 0, 0);
        }

        if (ocg == 0) {
            // q/k: two rounds (i=0: q rows 0-31, i=1: k rows 32-63)
            // Cs as [128px][32oc], 8B writes, chunk g ^= (px&3)
            #pragma unroll
            for (int i = 0; i < 2; i++) {
                int px = 32 * w + lr;
                #pragma unroll
                for (int g = 0; g < 4; g++) {
                    float v0 = acc[i][4*g+0] + biasS[32*i + 8*g + 4*lh + 0];
                    float v1 = acc[i][4*g+1] + biasS[32*i + 8*g + 4*lh + 1];
                    float v2 = acc[i][4*g+2] + biasS[32*i + 8*g + 4*lh + 2];
                    float v3 = acc[i][4*g+3] + biasS[32*i + 8*g + 4*lh + 3];
                    uint2 u; u.x = pack_bf_trunc(v0, v1); u.y = pack_bf_trunc(v2, v3);
                    int cp = g ^ (px & 3);
                    *(uint2*)&Cs[px * 32 + cp * 8 + 4 * lh] = u;
                }
                __syncthreads();
                #pragma unroll
                for (int i2 = 0; i2 < 2; i2++) {
                    int u4 = i2 * 256 + tid;
                    int hl = u4 >> 7, px2 = u4 & 127;
                    int cp = hl ^ (px2 & 3);
                    uint4 val = *(const uint4*)&Cs[px2 * 32 + cp * 8];
                    unsigned off = (unsigned)((b * 4 + hl) * HW + p0 + px2) * 8;
                    if (i == 0) *(uint4*)&qb[off] = val;
                    else        *(uint4*)&kb[off] = val;
                }
                __syncthreads();
            }
        } else {
            // v: two rounds of 32 oc; Cs as [32oc][128px], chunk (px>>3)^(oc&15)
            #pragma unroll
            for (int i = 0; i < 2; i++) {
                int px = 32 * w + lr;
                #pragma unroll
                for (int reg = 0; reg < 16; reg++) {
                    int m = (reg & 3) + 8 * (reg >> 2) + 4 * lh;
                    float v = acc[i][reg] + biasS[oc0 + 32 * i + m];
                    int cp = (px >> 3) ^ (m & 15);
                    Cs[m * 128 + cp * 8 + (px & 7)] =
                        (unsigned short)(__builtin_bit_cast(unsigned, v) >> 16);
                }
                __syncthreads();
                #pragma unroll
                for (int i2 = 0; i2 < 2; i2++) {
                    int u4 = i2 * 256 + tid;
                    int m = u4 >> 4, seg = u4 & 15;
                    int cp = seg ^ (m & 15);
                    uint4 val = *(const uint4*)&Cs[m * 128 + cp * 8];
                    *(uint4*)&vb[(unsigned)((b * 256 + oc0 - 64 + 32 * i + m) * HW
                                            + p0 + seg * 8)] = val;
                }
                __syncthreads();
            }
        }
    }
}

// ---------------------------------------------------------------------------
// Transpose q/k NHWC planes: 128x128 grid of 16B pixels, per bh-plane.
// ---------------------------------------------------------------------------
__global__ __launch_bounds__(256) void tqk_kernel(
    const unsigned short* __restrict__ qb, const unsigned short* __restrict__ kb,
    unsigned short* __restrict__ qt, unsigned short* __restrict__ kt)
{
    __shared__ uint4 t[32][33];
    const int plane = blockIdx.y;
    const int tile  = blockIdx.x;
    const int tx = tile & 3, ty = tile >> 2;
    const uint4* src = (const uint4*)(plane < 16 ? qb : kb) + (plane & 15) * HW;
    uint4*       dst = (uint4*)(plane < 16 ? qt : kt) + (plane & 15) * HW;
    const int c = threadIdx.x & 31, r0 = threadIdx.x >> 5;
    #pragma unroll
    for (int i = 0; i < 4; i++) {
        int r = r0 + i * 8;
        t[r][c] = src[(ty * 32 + r) * 128 + tx * 32 + c];
    }
    __syncthreads();
    #pragma unroll
    for (int i = 0; i < 4; i++) {
        int r = r0 + i * 8;
        dst[(tx * 32 + r) * 128 + ty * 32 + c] = t[c][r];
    }
}

// ---------------------------------------------------------------------------
// Transpose v planes (bf16 128x128), 64x64 tiles via LDS.
// ---------------------------------------------------------------------------
__global__ __launch_bounds__(256) void tv_kernel(
    const unsigned short* __restrict__ vb, unsigned short* __restrict__ vt)
{
    __shared__ unsigned short T[64][66];
    const int plane = blockIdx.y;
    const int tile  = blockIdx.x;
    const int tx = tile & 1, ty = tile >> 1;
    const unsigned* src = (const unsigned*)(vb + plane * HW);
    unsigned*       dst = (unsigned*)(vt + plane * HW);
    const int tid = threadIdx.x;
    #pragma unroll
    for (int i = 0; i < 8; i++) {
        int e = i * 256 + tid;
        int r = e >> 5, cp = e & 31;
        *(unsigned*)&T[r][2 * cp] = src[(ty * 64 + r) * 64 + tx * 32 + cp];
    }
    __syncthreads();
    #pragma unroll
    for (int i = 0; i < 8; i++) {
        int e = i * 256 + tid;
        int c = e >> 5, rp = e & 31;
        unsigned lo = T[2 * rp][c], hi = T[2 * rp + 1][c];
        dst[(tx * 64 + c) * 64 + ty * 32 + rp] = lo | (hi << 16);
    }
}

// ---------------------------------------------------------------------------
// MFMA attention v3b: in-register softmax. Each wave computes et = mfma(K-group
// kg, Q-group w) for kg=0..3, so it owns ALL 128 keys for its 32 queries
// (query = lane&31, same as the output epilogue). Row-sum = 64 in-reg adds +
// one shfl_xor(32). P is packed to bf16 unnormalized and redistributed into PV
// B-fragments. v3 used raw `v_permlane32_swap_b32` asm here and FAILED
// (absmax 468 -> garbage words outside the row-sum, i.e. corrupt exchange);
// v3b uses the unambiguous __shfl_xor(,32) + lh-select construction:
//   w0 = lh ? partnerX2 : X0 ; w1 = lh ? pX3 : X1
//   w2 = lh ? X2 : pX0       ; w3 = lh ? X3 : pX1
// (keys (r&3)+8*(r>>2)+4*lh; B-frag word m = keys 8*lh+2m,2m+1).
// Normalization deferred: between stages o *= s1/s0, epilogue gamma/s1.
// Both stages' V tiles preloaded into a 32KB double buffer -> ONE barrier.
// ---------------------------------------------------------------------------
__global__ __launch_bounds__(256, 4) void attn_kernel(
    const unsigned short* __restrict__ qb, const unsigned short* __restrict__ kb,
    const unsigned short* __restrict__ vb,
    const unsigned short* __restrict__ qt, const unsigned short* __restrict__ kt,
    const unsigned short* __restrict__ vt,
    const float* __restrict__ xin, const float* __restrict__ gamma,
    float* __restrict__ out)
{
    __shared__ __align__(16) unsigned short Vs[2][64 * 128];  // [ch][key], chunk ^= (ch&15)

    const int tid = threadIdx.x;
    const int y = blockIdx.x, bh = blockIdx.y;
    const int w = tid >> 6, l = tid & 63, lr = l & 31, lh = l >> 5;
    const float L2E = 1.4426950408889634f;

    // preload V for BOTH stages
    #pragma unroll
    for (int s = 0; s < 2; s++) {
        const unsigned short* vsrc = s ? vt : vb;
        #pragma unroll
        for (int i = 0; i < 4; i++) {
            int e = i * 256 + tid;
            int ch = e >> 4, sg = e & 15, sgp = sg ^ (ch & 15);
            *(uint4*)&Vs[s][ch * 128 + sgp * 8] =
                *(const uint4*)(vsrc + (bh * 64 + ch) * HW + y * 128 + sg * 8);
        }
    }
    __syncthreads();

    floatx16 z16 = {0,0,0,0,0,0,0,0,0,0,0,0,0,0,0,0};
    floatx16 o0 = z16, o1 = z16;
    short8 z8 = {0,0,0,0,0,0,0,0};
    float s0s = 1.0f;

    #pragma unroll
    for (int stage = 0; stage < 2; stage++) {
        const unsigned short* qsrc = (stage ? qt : qb) + (bh * 128 + y) * 1024;
        const unsigned short* ksrc = (stage ? kt : kb) + (bh * 128 + y) * 1024;
        short8 bf = z8;
        if (lh == 0) bf = *(const short8*)(qsrc + (32 * w + lr) * 8);

        float partial = 0.f;
        short8 pf[8];
        #pragma unroll
        for (int kg = 0; kg < 4; kg++) {
            short8 af = z8;
            if (lh == 0) af = *(const short8*)(ksrc + (32 * kg + lr) * 8);
            floatx16 e = __builtin_amdgcn_mfma_f32_32x32x16_bf16(af, bf, z16, 0, 0, 0);
            #pragma unroll
            for (int r = 0; r < 16; r++) {
                float p = exp2f(e[r] * L2E);   // no max-pass: |e| <~ 12
                e[r] = p;
                partial += p;
            }
            // pack unnormalized P into PV B-fragments (shfl_xor half-exchange)
            #pragma unroll
            for (int cc = 0; cc < 2; cc++) {
                unsigned X0 = pack_bf_trunc(e[8*cc+0], e[8*cc+1]);
                unsigned X1 = pack_bf_trunc(e[8*cc+2], e[8*cc+3]);
                unsigned X2 = pack_bf_trunc(e[8*cc+4], e[8*cc+5]);
                unsigned X3 = pack_bf_trunc(e[8*cc+6], e[8*cc+7]);
                unsigned pX0 = __shfl_xor(X0, 32);
                unsigned pX1 = __shfl_xor(X1, 32);
                unsigned pX2 = __shfl_xor(X2, 32);
                unsigned pX3 = __shfl_xor(X3, 32);
                union { unsigned u[4]; short8 s8; } t;
                t.u[0] = lh ? pX2 : X0;
                t.u[1] = lh ? pX3 : X1;
                t.u[2] = lh ? X2  : pX0;
                t.u[3] = lh ? X3  : pX1;
                pf[2 * kg + cc] = t.s8;
            }
        }
        float ssum = partial + __shfl_xor(partial, 32);
        if (stage == 1) {                 // rescale stage-0 output: rl0 = (s1/s0)*(1/s1)
            float f = ssum / s0s;
            #pragma unroll
            for (int r = 0; r < 16; r++) { o0[r] *= f; o1[r] *= f; }
        }
        s0s = ssum;

        #pragma unroll
        for (int ks = 0; ks < 8; ks++) {
            int cp = ((2 * ks + lh) ^ (lr & 15)) * 8;
            short8 v0 = *(const short8*)&Vs[stage][lr * 128 + cp];
            short8 v1 = *(const short8*)&Vs[stage][(32 + lr) * 128 + cp];
            o0 = __builtin_amdgcn_mfma_f32_32x32x16_bf16(v0, pf[ks], o0, 0, 0, 0);
            o1 = __builtin_amdgcn_mfma_f32_32x32x16_bf16(v1, pf[ks], o1, 0, 0, 0);
        }
    }

    const float gs = gamma[0] / s0s;      // g * rl1
    const int xq = 32 * w + lr;
    #pragma unroll
    for (int reg = 0; reg < 16; reg++) {
        int ch = (reg & 3) + 8 * (reg >> 2) + 4 * lh;
        int idx0 = (bh * 64 + ch) * HW + y * 128 + xq;
        int idx1 = (bh * 64 + 32 + ch) * HW + y * 128 + xq;
        out[idx0] = gs * o0[reg] + xin[idx0];
        out[idx1] = gs * o1[reg] + xin[idx1];
    }
}

extern "C" void kernel_launch(void* const* d_in, const int* in_sizes, int n_in,
                              void* d_out, int out_size, void* d_ws, size_t ws_size,
                              hipStream_t stream) {
    const float* x     = (const float*)d_in[0];
    const float* Wq    = (const float*)d_in[1];
    const float* bq    = (const float*)d_in[2];
    const float* Wk    = (const float*)d_in[3];
    const float* bk    = (const float*)d_in[4];
    const float* Wv    = (const float*)d_in[5];
    const float* bv    = (const float*)d_in[6];
    const float* gamma = (const float*)d_in[7];
    float* out = (float*)d_out;

    unsigned short* Wb   = (unsigned short*)d_ws;
    unsigned short* qb16 = Wb + 320 * 256;
    unsigned short* kb16 = qb16 + 16 * HW * 8;
    unsigned short* qt16 = kb16 + 16 * HW * 8;
    unsigned short* kt16 = qt16 + 16 * HW * 8;
    unsigned short* vb16 = kt16 + 16 * HW * 8;
    unsigned short* vt16 = vb16 + 1024 * HW;
    // xt (bf16 x transposed) lives in d_out: consumed by proj before attn writes.
    unsigned short* xt = (unsigned short*)d_out;

    castW_kernel<<<dim3(80), 256, 0, stream>>>(Wq, Wk, Wv, Wb);
    cast_xt_kernel<<<dim3(256, 4, 4), 256, 0, stream>>>(x, xt);
    proj_mfma_kernel<<<dim3(128, 4), 256, 0, stream>>>(Wb, xt, bq, bk, bv, qb16, kb16, vb16);
    tqk_kernel<<<dim3(16, 32), 256, 0, stream>>>(qb16, kb16, qt16, kt16);
    tv_kernel<<<dim3(4, 1024), 256, 0, stream>>>(vb16, vt16);
    attn_kernel<<<dim3(128, 16), 256, 0, stream>>>(qb16, kb16, vb16, qt16, kt16, vt16, x, gamma, out);
}

// Round 4
// 201.167 us; speedup vs baseline: 1.2590x; 1.2590x over previous
//
#include <hip/hip_runtime.h>

#define HW 16384   // 128*128

typedef __attribute__((ext_vector_type(8))) short short8;
typedef __attribute__((ext_vector_type(16))) float floatx16;
typedef __attribute__((ext_vector_type(4))) unsigned int uvec4;

__device__ inline unsigned short f2bf(float f) {
    unsigned u = __builtin_bit_cast(unsigned, f);
    u = (u + 0x7FFFu + ((u >> 16) & 1u)) >> 16;   // RNE
    return (unsigned short)u;
}

// pack two fp32 -> bf16x2 by truncation: one v_perm_b32
__device__ inline unsigned pack_bf_trunc(float lo, float hi) {
    return __builtin_amdgcn_perm(__builtin_bit_cast(unsigned, hi),
                                 __builtin_bit_cast(unsigned, lo), 0x07060302u);
}

// ---------------------------------------------------------------------------
// Cast W q/k/v -> bf16 Wb[320][256]: rows 0-31 q, 32-63 k, 64-319 v.
// ---------------------------------------------------------------------------
__global__ __launch_bounds__(256) void castW_kernel(
    const float* __restrict__ Wq, const float* __restrict__ Wk,
    const float* __restrict__ Wv, unsigned short* __restrict__ Wb)
{
    int idx4 = blockIdx.x * 256 + threadIdx.x;
    int e0 = idx4 * 4;
    int row = e0 >> 8, col = e0 & 255;
    const float* src = (row < 32) ? (Wq + row * 256 + col)
                     : (row < 64) ? (Wk + (row - 32) * 256 + col)
                                  : (Wv + (row - 64) * 256 + col);
    float4 v = *(const float4*)src;
    uint2 pk;
    pk.x = f2bf(v.x) | ((unsigned)f2bf(v.y) << 16);
    pk.y = f2bf(v.z) | ((unsigned)f2bf(v.w) << 16);
    *(uint2*)&Wb[e0] = pk;
}

// ---------------------------------------------------------------------------
// Cast + transpose x: [b][c][p] fp32 -> xt[b][p][c] bf16.  64c x 64p tiles.
// ---------------------------------------------------------------------------
__global__ __launch_bounds__(256) void cast_xt_kernel(
    const float* __restrict__ x, unsigned short* __restrict__ xt)
{
    __shared__ unsigned short T[64][66];
    const int tid = threadIdx.x;
    const int p0 = blockIdx.x * 64;
    const int c0 = blockIdx.y * 64;
    const int b  = blockIdx.z;
    #pragma unroll
    for (int i = 0; i < 4; i++) {
        int e = i * 256 + tid;
        int c = e >> 4, seg = e & 15;
        float4 v = *(const float4*)&x[((b * 256 + c0 + c) << 14) + p0 + seg * 4];
        ((unsigned*)&T[c][seg * 4])[0] = f2bf(v.x) | ((unsigned)f2bf(v.y) << 16);
        ((unsigned*)&T[c][seg * 4])[1] = f2bf(v.z) | ((unsigned)f2bf(v.w) << 16);
    }
    __syncthreads();
    #pragma unroll
    for (int i = 0; i < 2; i++) {
        int e = i * 256 + tid;
        int p = e >> 3, cs = e & 7;
        unsigned short t[8];
        #pragma unroll
        for (int j = 0; j < 8; j++) t[j] = T[cs * 8 + j][p];
        uint4 pk;
        pk.x = t[0] | ((unsigned)t[1] << 16);
        pk.y = t[2] | ((unsigned)t[3] << 16);
        pk.z = t[4] | ((unsigned)t[5] << 16);
        pk.w = t[6] | ((unsigned)t[7] << 16);
        *(uint4*)&xt[(((b << 14) + p0 + p) << 8) + c0 + cs * 8] = pk;
    }
}

// ---------------------------------------------------------------------------
// MFMA projection (R0-proven v1). As/Bs XOR-swizzled on 16B chunks
// (conflict-free b128), LDS-assembled coalesced epilogue (Bs reused as
// C-staging).
// ---------------------------------------------------------------------------
__global__ __launch_bounds__(256, 3) void proj_mfma_kernel(
    const unsigned short* __restrict__ Wb, const unsigned short* __restrict__ xt,
    const float* __restrict__ bq, const float* __restrict__ bk,
    const float* __restrict__ bv,
    unsigned short* __restrict__ qb, unsigned short* __restrict__ kb,
    unsigned short* __restrict__ vb)
{
    __shared__ __align__(16) unsigned short As[64 * 64];    // [oc][k], chunk c^=(row&7)
    __shared__ __align__(16) unsigned short Bs[256 * 64];   // [px][k], chunk c^=(row&7)
    __shared__ float biasS[64];
    const int tid = threadIdx.x;
    const int p0  = blockIdx.x * 256;
    const int oc0 = blockIdx.y * 64;
    const int b   = blockIdx.z;
    const int w = tid >> 6, lr = tid & 31, lh = (tid & 63) >> 5;

    if (tid < 64) biasS[tid] = (oc0 == 0) ? ((tid < 32) ? bq[tid] : bk[tid - 32])
                                          : bv[oc0 - 64 + tid];

    floatx16 z16 = {0,0,0,0,0,0,0,0,0,0,0,0,0,0,0,0};
    floatx16 acc[2][2] = {{z16, z16}, {z16, z16}};
    const int bpx = (b << 14) + p0;

    for (int kc = 0; kc < 256; kc += 64) {
        if (kc) __syncthreads();
        #pragma unroll
        for (int i = 0; i < 2; i++) {
            int e = i * 256 + tid;
            int row = e >> 3, seg = e & 7, cp = seg ^ (row & 7);
            *(uint4*)&As[row * 64 + cp * 8] =
                *(const uint4*)&Wb[(oc0 + row) * 256 + kc + seg * 8];
        }
        #pragma unroll
        for (int i = 0; i < 8; i++) {
            int e = i * 256 + tid;
            int row = e >> 3, seg = e & 7, cp = seg ^ (row & 7);
            *(uint4*)&Bs[row * 64 + cp * 8] =
                *(const uint4*)&xt[((bpx + row) << 8) + kc + seg * 8];
        }
        __syncthreads();
        #pragma unroll
        for (int ks = 0; ks < 4; ks++) {
            int c = 2 * ks + lh;
            int cx = (c ^ (lr & 7)) * 8;
            short8 af0 = *(const short8*)&As[lr * 64 + cx];
            short8 af1 = *(const short8*)&As[(32 + lr) * 64 + cx];
            short8 bf0 = *(const short8*)&Bs[(64 * w + lr) * 64 + cx];
            short8 bf1 = *(const short8*)&Bs[(64 * w + 32 + lr) * 64 + cx];
            acc[0][0] = __builtin_amdgcn_mfma_f32_32x32x16_bf16(af0, bf0, acc[0][0], 0, 0, 0);
            acc[0][1] = __builtin_amdgcn_mfma_f32_32x32x16_bf16(af0, bf1, acc[0][1], 0, 0, 0);
            acc[1][0] = __builtin_amdgcn_mfma_f32_32x32x16_bf16(af1, bf0, acc[1][0], 0, 0, 0);
            acc[1][1] = __builtin_amdgcn_mfma_f32_32x32x16_bf16(af1, bf1, acc[1][1], 0, 0, 0);
        }
    }

    __syncthreads();   // Bs reads done; reuse as C-staging
    if (oc0 == 0) {
        // Cq[px 256][oc 64], 16B-chunk swizzle c^=(px&7). oc chunk = head (q:0-3, k:4-7)
        unsigned short* Cq = Bs;
        #pragma unroll
        for (int i = 0; i < 2; i++) {
            #pragma unroll
            for (int j = 0; j < 2; j++) {
                int px = 64 * w + 32 * j + lr;
                #pragma unroll
                for (int g = 0; g < 4; g++) {
                    float v0 = acc[i][j][4*g+0] + biasS[32*i + 8*g + 4*lh + 0];
                    float v1 = acc[i][j][4*g+1] + biasS[32*i + 8*g + 4*lh + 1];
                    float v2 = acc[i][j][4*g+2] + biasS[32*i + 8*g + 4*lh + 2];
                    float v3 = acc[i][j][4*g+3] + biasS[32*i + 8*g + 4*lh + 3];
                    uint2 u; u.x = pack_bf_trunc(v0, v1); u.y = pack_bf_trunc(v2, v3);
                    int cp = (4 * i + g) ^ (px & 7);
                    *(uint2*)&Cq[px * 64 + cp * 8 + 4 * lh] = u;
                }
            }
        }
        __syncthreads();
        #pragma unroll
        for (int i = 0; i < 8; i++) {   // head-major coalesced stores
            int px = tid;
            int cp = i ^ (px & 7);
            uint4 val = *(const uint4*)&Cq[px * 64 + cp * 8];
            if (i < 4) *(uint4*)&qb[(unsigned)((b * 4 + i)     * HW + p0 + px) * 8] = val;
            else       *(uint4*)&kb[(unsigned)((b * 4 + i - 4) * HW + p0 + px) * 8] = val;
        }
    } else {
        // Cv[oc 64][px 256], chunk (px>>3) swizzled by oc&31
        unsigned short* Cv = Bs;
        #pragma unroll
        for (int i = 0; i < 2; i++) {
            #pragma unroll
            for (int j = 0; j < 2; j++) {
                int px = 64 * w + 32 * j + lr;
                #pragma unroll
                for (int reg = 0; reg < 16; reg++) {
                    int oc = 32 * i + (reg & 3) + 8 * (reg >> 2) + 4 * lh;
                    float v = acc[i][j][reg] + biasS[oc];
                    int cp = (px >> 3) ^ (oc & 31);
                    Cv[oc * 256 + cp * 8 + (px & 7)] =
                        (unsigned short)(__builtin_bit_cast(unsigned, v) >> 16);
                }
            }
        }
        __syncthreads();
        #pragma unroll
        for (int i = 0; i < 8; i++) {
            int u = i * 256 + tid;
            int oc = u >> 5, seg = u & 31;
            int cp = seg ^ (oc & 31);
            uint4 val = *(const uint4*)&Cv[oc * 256 + cp * 8];
            *(uint4*)&vb[(unsigned)(b * 256 + oc0 - 64 + oc) * HW + p0 + seg * 8] = val;
        }
    }
}

// ---------------------------------------------------------------------------
// Transpose q/k NHWC planes: 128x128 grid of 16B pixels, per bh-plane.
// ---------------------------------------------------------------------------
__global__ __launch_bounds__(256) void tqk_kernel(
    const unsigned short* __restrict__ qb, const unsigned short* __restrict__ kb,
    unsigned short* __restrict__ qt, unsigned short* __restrict__ kt)
{
    __shared__ uint4 t[32][33];
    const int plane = blockIdx.y;
    const int tile  = blockIdx.x;
    const int tx = tile & 3, ty = tile >> 2;
    const uint4* src = (const uint4*)(plane < 16 ? qb : kb) + (plane & 15) * HW;
    uint4*       dst = (uint4*)(plane < 16 ? qt : kt) + (plane & 15) * HW;
    const int c = threadIdx.x & 31, r0 = threadIdx.x >> 5;
    #pragma unroll
    for (int i = 0; i < 4; i++) {
        int r = r0 + i * 8;
        t[r][c] = src[(ty * 32 + r) * 128 + tx * 32 + c];
    }
    __syncthreads();
    #pragma unroll
    for (int i = 0; i < 4; i++) {
        int r = r0 + i * 8;
        dst[(tx * 32 + r) * 128 + ty * 32 + c] = t[c][r];
    }
}

// ---------------------------------------------------------------------------
// Transpose v planes (bf16 128x128), 64x64 tiles via LDS.
// ---------------------------------------------------------------------------
__global__ __launch_bounds__(256) void tv_kernel(
    const unsigned short* __restrict__ vb, unsigned short* __restrict__ vt)
{
    __shared__ unsigned short T[64][66];
    const int plane = blockIdx.y;
    const int tile  = blockIdx.x;
    const int tx = tile & 1, ty = tile >> 1;
    const unsigned* src = (const unsigned*)(vb + plane * HW);
    unsigned*       dst = (unsigned*)(vt + plane * HW);
    const int tid = threadIdx.x;
    #pragma unroll
    for (int i = 0; i < 8; i++) {
        int e = i * 256 + tid;
        int r = e >> 5, cp = e & 31;
        *(unsigned*)&T[r][2 * cp] = src[(ty * 64 + r) * 64 + tx * 32 + cp];
    }
    __syncthreads();
    #pragma unroll
    for (int i = 0; i < 8; i++) {
        int e = i * 256 + tid;
        int c = e >> 5, rp = e & 31;
        unsigned lo = T[2 * rp][c], hi = T[2 * rp + 1][c];
        dst[(tx * 64 + c) * 64 + ty * 32 + rp] = lo | (hi << 16);
    }
}

// ---------------------------------------------------------------------------
// MFMA attention v3c: in-register softmax (et = mfma(K-group kg, Q-group w),
// wave owns all 128 keys for its 32 queries). Row-sum = in-reg adds + one
// shfl_xor(32). P packed unnormalized into PV B-fragments via shfl_xor(32) +
// lh-select (R2-verified correct). Deferred normalization across stages.
// R2 post-mortem fixes:
//  - union type-punning -> ext_vector + bit_cast (no chance of scratch;
//    R2 showed VGPR squeezed to 64 + ~74MB phantom HBM traffic)
//  - __launch_bounds__(256,2): give the allocator headroom (LDS 32KB still
//    allows 5 blocks/CU; no reason to squeeze to 64 VGPRs)
//  - __syncthreads() before the epilogue: re-converge drifted waves so the
//    4x128B adjacent out-stores per line-pair coalesce in L2.
// ---------------------------------------------------------------------------
__global__ __launch_bounds__(256, 2) void attn_kernel(
    const unsigned short* __restrict__ qb, const unsigned short* __restrict__ kb,
    const unsigned short* __restrict__ vb,
    const unsigned short* __restrict__ qt, const unsigned short* __restrict__ kt,
    const unsigned short* __restrict__ vt,
    const float* __restrict__ xin, const float* __restrict__ gamma,
    float* __restrict__ out)
{
    __shared__ __align__(16) unsigned short Vs[2][64 * 128];  // [ch][key], chunk ^= (ch&15)

    const int tid = threadIdx.x;
    const int y = blockIdx.x, bh = blockIdx.y;
    const int w = tid >> 6, l = tid & 63, lr = l & 31, lh = l >> 5;
    const float L2E = 1.4426950408889634f;

    // preload V for BOTH stages
    #pragma unroll
    for (int s = 0; s < 2; s++) {
        const unsigned short* vsrc = s ? vt : vb;
        #pragma unroll
        for (int i = 0; i < 4; i++) {
            int e = i * 256 + tid;
            int ch = e >> 4, sg = e & 15, sgp = sg ^ (ch & 15);
            *(uint4*)&Vs[s][ch * 128 + sgp * 8] =
                *(const uint4*)(vsrc + (bh * 64 + ch) * HW + y * 128 + sg * 8);
        }
    }
    __syncthreads();

    floatx16 z16 = {0,0,0,0,0,0,0,0,0,0,0,0,0,0,0,0};
    floatx16 o0 = z16, o1 = z16;
    short8 z8 = {0,0,0,0,0,0,0,0};
    float s0s = 1.0f;

    #pragma unroll
    for (int stage = 0; stage < 2; stage++) {
        const unsigned short* qsrc = (stage ? qt : qb) + (bh * 128 + y) * 1024;
        const unsigned short* ksrc = (stage ? kt : kb) + (bh * 128 + y) * 1024;
        short8 bf = z8;
        if (lh == 0) bf = *(const short8*)(qsrc + (32 * w + lr) * 8);

        float partial = 0.f;
        short8 pf[8];
        #pragma unroll
        for (int kg = 0; kg < 4; kg++) {
            short8 af = z8;
            if (lh == 0) af = *(const short8*)(ksrc + (32 * kg + lr) * 8);
            floatx16 e = __builtin_amdgcn_mfma_f32_32x32x16_bf16(af, bf, z16, 0, 0, 0);
            #pragma unroll
            for (int r = 0; r < 16; r++) {
                float p = exp2f(e[r] * L2E);   // no max-pass: |e| <~ 12
                e[r] = p;
                partial += p;
            }
            // pack unnormalized P into PV B-fragments (shfl_xor half-exchange)
            #pragma unroll
            for (int cc = 0; cc < 2; cc++) {
                unsigned X0 = pack_bf_trunc(e[8*cc+0], e[8*cc+1]);
                unsigned X1 = pack_bf_trunc(e[8*cc+2], e[8*cc+3]);
                unsigned X2 = pack_bf_trunc(e[8*cc+4], e[8*cc+5]);
                unsigned X3 = pack_bf_trunc(e[8*cc+6], e[8*cc+7]);
                unsigned pX0 = __shfl_xor(X0, 32);
                unsigned pX1 = __shfl_xor(X1, 32);
                unsigned pX2 = __shfl_xor(X2, 32);
                unsigned pX3 = __shfl_xor(X3, 32);
                uvec4 t;
                t.x = lh ? pX2 : X0;
                t.y = lh ? pX3 : X1;
                t.z = lh ? X2  : pX0;
                t.w = lh ? X3  : pX1;
                pf[2 * kg + cc] = __builtin_bit_cast(short8, t);
            }
        }
        float ssum = partial + __shfl_xor(partial, 32);
        if (stage == 1) {                 // rescale stage-0 output: rl0 = (s1/s0)*(1/s1)
            float f = ssum / s0s;
            #pragma unroll
            for (int r = 0; r < 16; r++) { o0[r] *= f; o1[r] *= f; }
        }
        s0s = ssum;

        #pragma unroll
        for (int ks = 0; ks < 8; ks++) {
            int cp = ((2 * ks + lh) ^ (lr & 15)) * 8;
            short8 v0 = *(const short8*)&Vs[stage][lr * 128 + cp];
            short8 v1 = *(const short8*)&Vs[stage][(32 + lr) * 128 + cp];
            o0 = __builtin_amdgcn_mfma_f32_32x32x16_bf16(v0, pf[ks], o0, 0, 0, 0);
            o1 = __builtin_amdgcn_mfma_f32_32x32x16_bf16(v1, pf[ks], o1, 0, 0, 0);
        }
    }

    __syncthreads();   // re-converge waves: adjacent 128B out-stores coalesce

    const float gs = gamma[0] / s0s;      // g * rl1
    const int xq = 32 * w + lr;
    #pragma unroll
    for (int reg = 0; reg < 16; reg++) {
        int ch = (reg & 3) + 8 * (reg >> 2) + 4 * lh;
        int idx0 = (bh * 64 + ch) * HW + y * 128 + xq;
        int idx1 = (bh * 64 + 32 + ch) * HW + y * 128 + xq;
        out[idx0] = gs * o0[reg] + xin[idx0];
        out[idx1] = gs * o1[reg] + xin[idx1];
    }
}

extern "C" void kernel_launch(void* const* d_in, const int* in_sizes, int n_in,
                              void* d_out, int out_size, void* d_ws, size_t ws_size,
                              hipStream_t stream) {
    const float* x     = (const float*)d_in[0];
    const float* Wq    = (const float*)d_in[1];
    const float* bq    = (const float*)d_in[2];
    const float* Wk    = (const float*)d_in[3];
    const float* bk    = (const float*)d_in[4];
    const float* Wv    = (const float*)d_in[5];
    const float* bv    = (const float*)d_in[6];
    const float* gamma = (const float*)d_in[7];
    float* out = (float*)d_out;

    unsigned short* Wb   = (unsigned short*)d_ws;
    unsigned short* qb16 = Wb + 320 * 256;
    unsigned short* kb16 = qb16 + 16 * HW * 8;
    unsigned short* qt16 = kb16 + 16 * HW * 8;
    unsigned short* kt16 = qt16 + 16 * HW * 8;
    unsigned short* vb16 = kt16 + 16 * HW * 8;
    unsigned short* vt16 = vb16 + 1024 * HW;
    // xt (bf16 x transposed) lives in d_out: consumed by proj before attn writes.
    unsigned short* xt = (unsigned short*)d_out;

    castW_kernel<<<dim3(80), 256, 0, stream>>>(Wq, Wk, Wv, Wb);
    cast_xt_kernel<<<dim3(256, 4, 4), 256, 0, stream>>>(x, xt);
    proj_mfma_kernel<<<dim3(64, 5, 4), 256, 0, stream>>>(Wb, xt, bq, bk, bv, qb16, kb16, vb16);
    tqk_kernel<<<dim3(16, 32), 256, 0, stream>>>(qb16, kb16, qt16, kt16);
    tv_kernel<<<dim3(4, 1024), 256, 0, stream>>>(vb16, vt16);
    attn_kernel<<<dim3(128, 16), 256, 0, stream>>>(qb16, kb16, vb16, qt16, kt16, vt16, x, gamma, out);
}

// Round 5
// 198.865 us; speedup vs baseline: 1.2736x; 1.0116x over previous
//
#include <hip/hip_runtime.h>

#define HW 16384   // 128*128

typedef __attribute__((ext_vector_type(8))) short short8;
typedef __attribute__((ext_vector_type(16))) float floatx16;
typedef __attribute__((ext_vector_type(4))) unsigned int uvec4;

__device__ inline unsigned short f2bf(float f) {
    unsigned u = __builtin_bit_cast(unsigned, f);
    u = (u + 0x7FFFu + ((u >> 16) & 1u)) >> 16;   // RNE
    return (unsigned short)u;
}

// pack two fp32 -> bf16x2 by truncation: one v_perm_b32
__device__ inline unsigned pack_bf_trunc(float lo, float hi) {
    return __builtin_amdgcn_perm(__builtin_bit_cast(unsigned, hi),
                                 __builtin_bit_cast(unsigned, lo), 0x07060302u);
}

// ---------------------------------------------------------------------------
// Cast + transpose x: [b][c][p] fp32 -> xt[b][p][c] bf16.  64c x 64p tiles.
// Also folds the W-cast (former castW_kernel) into 80 of the 4096 blocks:
// Wb[320][256] bf16, rows 0-31 q (PRE-SCALED by log2e: folds the softmax
// L2E multiply into q so attn uses exp2 directly), 32-63 k, 64-319 v.
// ---------------------------------------------------------------------------
__global__ __launch_bounds__(256) void cast_xt_kernel(
    const float* __restrict__ x,
    const float* __restrict__ Wq, const float* __restrict__ Wk,
    const float* __restrict__ Wv, unsigned short* __restrict__ Wb,
    unsigned short* __restrict__ xt)
{
    __shared__ unsigned short T[64][66];
    const int tid = threadIdx.x;
    const int p0 = blockIdx.x * 64;
    const int c0 = blockIdx.y * 64;
    const int b  = blockIdx.z;

    if (b == 0 && blockIdx.y == 0 && blockIdx.x < 80) {   // folded castW
        int e0 = (blockIdx.x * 256 + tid) * 4;
        int row = e0 >> 8, col = e0 & 255;
        const float* src = (row < 32) ? (Wq + row * 256 + col)
                         : (row < 64) ? (Wk + (row - 32) * 256 + col)
                                      : (Wv + (row - 64) * 256 + col);
        float4 v = *(const float4*)src;
        if (row < 32) {   // q rows: fold log2(e)
            const float L2E = 1.4426950408889634f;
            v.x *= L2E; v.y *= L2E; v.z *= L2E; v.w *= L2E;
        }
        uint2 pk;
        pk.x = f2bf(v.x) | ((unsigned)f2bf(v.y) << 16);
        pk.y = f2bf(v.z) | ((unsigned)f2bf(v.w) << 16);
        *(uint2*)&Wb[e0] = pk;
    }

    #pragma unroll
    for (int i = 0; i < 4; i++) {
        int e = i * 256 + tid;
        int c = e >> 4, seg = e & 15;
        float4 v = *(const float4*)&x[((b * 256 + c0 + c) << 14) + p0 + seg * 4];
        ((unsigned*)&T[c][seg * 4])[0] = f2bf(v.x) | ((unsigned)f2bf(v.y) << 16);
        ((unsigned*)&T[c][seg * 4])[1] = f2bf(v.z) | ((unsigned)f2bf(v.w) << 16);
    }
    __syncthreads();
    #pragma unroll
    for (int i = 0; i < 2; i++) {
        int e = i * 256 + tid;
        int p = e >> 3, cs = e & 7;
        unsigned short t[8];
        #pragma unroll
        for (int j = 0; j < 8; j++) t[j] = T[cs * 8 + j][p];
        uint4 pk;
        pk.x = t[0] | ((unsigned)t[1] << 16);
        pk.y = t[2] | ((unsigned)t[3] << 16);
        pk.z = t[4] | ((unsigned)t[5] << 16);
        pk.w = t[6] | ((unsigned)t[7] << 16);
        *(uint4*)&xt[(((b << 14) + p0 + p) << 8) + c0 + cs * 8] = pk;
    }
}

// ---------------------------------------------------------------------------
// MFMA projection (R0-proven v1). As/Bs XOR-swizzled on 16B chunks
// (conflict-free b128), LDS-assembled coalesced epilogue (Bs reused as
// C-staging).  bq scaled by log2e to match the q-row scaling of Wb.
// ---------------------------------------------------------------------------
__global__ __launch_bounds__(256, 3) void proj_mfma_kernel(
    const unsigned short* __restrict__ Wb, const unsigned short* __restrict__ xt,
    const float* __restrict__ bq, const float* __restrict__ bk,
    const float* __restrict__ bv,
    unsigned short* __restrict__ qb, unsigned short* __restrict__ kb,
    unsigned short* __restrict__ vb)
{
    __shared__ __align__(16) unsigned short As[64 * 64];    // [oc][k], chunk c^=(row&7)
    __shared__ __align__(16) unsigned short Bs[256 * 64];   // [px][k], chunk c^=(row&7)
    __shared__ float biasS[64];
    const int tid = threadIdx.x;
    const int p0  = blockIdx.x * 256;
    const int oc0 = blockIdx.y * 64;
    const int b   = blockIdx.z;
    const int w = tid >> 6, lr = tid & 31, lh = (tid & 63) >> 5;

    if (tid < 64) biasS[tid] = (oc0 == 0)
        ? ((tid < 32) ? bq[tid] * 1.4426950408889634f : bk[tid - 32])
        : bv[oc0 - 64 + tid];

    floatx16 z16 = {0,0,0,0,0,0,0,0,0,0,0,0,0,0,0,0};
    floatx16 acc[2][2] = {{z16, z16}, {z16, z16}};
    const int bpx = (b << 14) + p0;

    for (int kc = 0; kc < 256; kc += 64) {
        if (kc) __syncthreads();
        #pragma unroll
        for (int i = 0; i < 2; i++) {
            int e = i * 256 + tid;
            int row = e >> 3, seg = e & 7, cp = seg ^ (row & 7);
            *(uint4*)&As[row * 64 + cp * 8] =
                *(const uint4*)&Wb[(oc0 + row) * 256 + kc + seg * 8];
        }
        #pragma unroll
        for (int i = 0; i < 8; i++) {
            int e = i * 256 + tid;
            int row = e >> 3, seg = e & 7, cp = seg ^ (row & 7);
            *(uint4*)&Bs[row * 64 + cp * 8] =
                *(const uint4*)&xt[((bpx + row) << 8) + kc + seg * 8];
        }
        __syncthreads();
        #pragma unroll
        for (int ks = 0; ks < 4; ks++) {
            int c = 2 * ks + lh;
            int cx = (c ^ (lr & 7)) * 8;
            short8 af0 = *(const short8*)&As[lr * 64 + cx];
            short8 af1 = *(const short8*)&As[(32 + lr) * 64 + cx];
            short8 bf0 = *(const short8*)&Bs[(64 * w + lr) * 64 + cx];
            short8 bf1 = *(const short8*)&Bs[(64 * w + 32 + lr) * 64 + cx];
            acc[0][0] = __builtin_amdgcn_mfma_f32_32x32x16_bf16(af0, bf0, acc[0][0], 0, 0, 0);
            acc[0][1] = __builtin_amdgcn_mfma_f32_32x32x16_bf16(af0, bf1, acc[0][1], 0, 0, 0);
            acc[1][0] = __builtin_amdgcn_mfma_f32_32x32x16_bf16(af1, bf0, acc[1][0], 0, 0, 0);
            acc[1][1] = __builtin_amdgcn_mfma_f32_32x32x16_bf16(af1, bf1, acc[1][1], 0, 0, 0);
        }
    }

    __syncthreads();   // Bs reads done; reuse as C-staging
    if (oc0 == 0) {
        // Cq[px 256][oc 64], 16B-chunk swizzle c^=(px&7). oc chunk = head (q:0-3, k:4-7)
        unsigned short* Cq = Bs;
        #pragma unroll
        for (int i = 0; i < 2; i++) {
            #pragma unroll
            for (int j = 0; j < 2; j++) {
                int px = 64 * w + 32 * j + lr;
                #pragma unroll
                for (int g = 0; g < 4; g++) {
                    float v0 = acc[i][j][4*g+0] + biasS[32*i + 8*g + 4*lh + 0];
                    float v1 = acc[i][j][4*g+1] + biasS[32*i + 8*g + 4*lh + 1];
                    float v2 = acc[i][j][4*g+2] + biasS[32*i + 8*g + 4*lh + 2];
                    float v3 = acc[i][j][4*g+3] + biasS[32*i + 8*g + 4*lh + 3];
                    uint2 u; u.x = pack_bf_trunc(v0, v1); u.y = pack_bf_trunc(v2, v3);
                    int cp = (4 * i + g) ^ (px & 7);
                    *(uint2*)&Cq[px * 64 + cp * 8 + 4 * lh] = u;
                }
            }
        }
        __syncthreads();
        #pragma unroll
        for (int i = 0; i < 8; i++) {   // head-major coalesced stores
            int px = tid;
            int cp = i ^ (px & 7);
            uint4 val = *(const uint4*)&Cq[px * 64 + cp * 8];
            if (i < 4) *(uint4*)&qb[(unsigned)((b * 4 + i)     * HW + p0 + px) * 8] = val;
            else       *(uint4*)&kb[(unsigned)((b * 4 + i - 4) * HW + p0 + px) * 8] = val;
        }
    } else {
        // Cv[oc 64][px 256], chunk (px>>3) swizzled by oc&31
        unsigned short* Cv = Bs;
        #pragma unroll
        for (int i = 0; i < 2; i++) {
            #pragma unroll
            for (int j = 0; j < 2; j++) {
                int px = 64 * w + 32 * j + lr;
                #pragma unroll
                for (int reg = 0; reg < 16; reg++) {
                    int oc = 32 * i + (reg & 3) + 8 * (reg >> 2) + 4 * lh;
                    float v = acc[i][j][reg] + biasS[oc];
                    int cp = (px >> 3) ^ (oc & 31);
                    Cv[oc * 256 + cp * 8 + (px & 7)] =
                        (unsigned short)(__builtin_bit_cast(unsigned, v) >> 16);
                }
            }
        }
        __syncthreads();
        #pragma unroll
        for (int i = 0; i < 8; i++) {
            int u = i * 256 + tid;
            int oc = u >> 5, seg = u & 31;
            int cp = seg ^ (oc & 31);
            uint4 val = *(const uint4*)&Cv[oc * 256 + cp * 8];
            *(uint4*)&vb[(unsigned)(b * 256 + oc0 - 64 + oc) * HW + p0 + seg * 8] = val;
        }
    }
}

// ---------------------------------------------------------------------------
// Transpose q/k NHWC planes: 128x128 grid of 16B pixels, per bh-plane.
// ---------------------------------------------------------------------------
__global__ __launch_bounds__(256) void tqk_kernel(
    const unsigned short* __restrict__ qb, const unsigned short* __restrict__ kb,
    unsigned short* __restrict__ qt, unsigned short* __restrict__ kt)
{
    __shared__ uint4 t[32][33];
    const int plane = blockIdx.y;
    const int tile  = blockIdx.x;
    const int tx = tile & 3, ty = tile >> 2;
    const uint4* src = (const uint4*)(plane < 16 ? qb : kb) + (plane & 15) * HW;
    uint4*       dst = (uint4*)(plane < 16 ? qt : kt) + (plane & 15) * HW;
    const int c = threadIdx.x & 31, r0 = threadIdx.x >> 5;
    #pragma unroll
    for (int i = 0; i < 4; i++) {
        int r = r0 + i * 8;
        t[r][c] = src[(ty * 32 + r) * 128 + tx * 32 + c];
    }
    __syncthreads();
    #pragma unroll
    for (int i = 0; i < 4; i++) {
        int r = r0 + i * 8;
        dst[(tx * 32 + r) * 128 + ty * 32 + c] = t[c][r];
    }
}

// ---------------------------------------------------------------------------
// Transpose v planes (bf16 128x128), 64x64 tiles via LDS.
// ---------------------------------------------------------------------------
__global__ __launch_bounds__(256) void tv_kernel(
    const unsigned short* __restrict__ vb, unsigned short* __restrict__ vt)
{
    __shared__ unsigned short T[64][66];
    const int plane = blockIdx.y;
    const int tile  = blockIdx.x;
    const int tx = tile & 1, ty = tile >> 1;
    const unsigned* src = (const unsigned*)(vb + plane * HW);
    unsigned*       dst = (unsigned*)(vt + plane * HW);
    const int tid = threadIdx.x;
    #pragma unroll
    for (int i = 0; i < 8; i++) {
        int e = i * 256 + tid;
        int r = e >> 5, cp = e & 31;
        *(unsigned*)&T[r][2 * cp] = src[(ty * 64 + r) * 64 + tx * 32 + cp];
    }
    __syncthreads();
    #pragma unroll
    for (int i = 0; i < 8; i++) {
        int e = i * 256 + tid;
        int c = e >> 5, rp = e & 31;
        unsigned lo = T[2 * rp][c], hi = T[2 * rp + 1][c];
        dst[(tx * 64 + c) * 64 + ty * 32 + rp] = lo | (hi << 16);
    }
}

// ---------------------------------------------------------------------------
// MFMA attention v4: in-register softmax with per-kg pack->PV interleave and
// SEPARATE per-stage accumulators (the two stages are independent softmaxes:
// out = g*(o_h/s0 + o_v/s1) + x). vs v3c:
//  - PV MFMAs issued immediately after each key-group's exp/pack (PV
//    accumulation is order-free) -> kg's MFMAs overlap next kg's exp on the
//    VALU pipe; pf[8] live range (32 VGPRs) eliminated.
//  - no inter-stage o-rescale pass (-32 mul/thread); epilogue combines with
//    two FMAs using per-stage reciprocals.
//  - q pre-scaled by log2e at cast time -> exp2f direct (-128 mul/thread).
// ---------------------------------------------------------------------------
__global__ __launch_bounds__(256, 2) void attn_kernel(
    const unsigned short* __restrict__ qb, const unsigned short* __restrict__ kb,
    const unsigned short* __restrict__ vb,
    const unsigned short* __restrict__ qt, const unsigned short* __restrict__ kt,
    const unsigned short* __restrict__ vt,
    const float* __restrict__ xin, const float* __restrict__ gamma,
    float* __restrict__ out)
{
    __shared__ __align__(16) unsigned short Vs[2][64 * 128];  // [ch][key], chunk ^= (ch&15)

    const int tid = threadIdx.x;
    const int y = blockIdx.x, bh = blockIdx.y;
    const int w = tid >> 6, l = tid & 63, lr = l & 31, lh = l >> 5;

    // preload V for BOTH stages
    #pragma unroll
    for (int s = 0; s < 2; s++) {
        const unsigned short* vsrc = s ? vt : vb;
        #pragma unroll
        for (int i = 0; i < 4; i++) {
            int e = i * 256 + tid;
            int ch = e >> 4, sg = e & 15, sgp = sg ^ (ch & 15);
            *(uint4*)&Vs[s][ch * 128 + sgp * 8] =
                *(const uint4*)(vsrc + (bh * 64 + ch) * HW + y * 128 + sg * 8);
        }
    }
    __syncthreads();

    floatx16 z16 = {0,0,0,0,0,0,0,0,0,0,0,0,0,0,0,0};
    floatx16 oh0 = z16, oh1 = z16;   // stage 0 (horizontal) accumulators
    floatx16 ov0 = z16, ov1 = z16;   // stage 1 (vertical)
    short8 z8 = {0,0,0,0,0,0,0,0};
    float ssA = 1.0f, ssB = 1.0f;

    #pragma unroll
    for (int stage = 0; stage < 2; stage++) {
        const unsigned short* qsrc = (stage ? qt : qb) + (bh * 128 + y) * 1024;
        const unsigned short* ksrc = (stage ? kt : kb) + (bh * 128 + y) * 1024;
        short8 bf = z8;
        if (lh == 0) bf = *(const short8*)(qsrc + (32 * w + lr) * 8);

        // all 4 QK^T MFMAs up-front (independent, pipeline back-to-back)
        floatx16 et[4];
        #pragma unroll
        for (int kg = 0; kg < 4; kg++) {
            short8 af = z8;
            if (lh == 0) af = *(const short8*)(ksrc + (32 * kg + lr) * 8);
            et[kg] = __builtin_amdgcn_mfma_f32_32x32x16_bf16(af, bf, z16, 0, 0, 0);
        }

        float partial = 0.f;
        #pragma unroll
        for (int kg = 0; kg < 4; kg++) {
            floatx16 e = et[kg];
            #pragma unroll
            for (int r = 0; r < 16; r++) {
                float p = exp2f(e[r]);   // L2E folded into q; no max-pass (|e| small)
                e[r] = p;
                partial += p;
            }
            // pack unnormalized P into PV B-fragments (shfl_xor half-exchange),
            // issue this key-group's PV MFMAs immediately (accumulation is
            // order-free) so they overlap the next kg's exp.
            #pragma unroll
            for (int cc = 0; cc < 2; cc++) {
                unsigned X0 = pack_bf_trunc(e[8*cc+0], e[8*cc+1]);
                unsigned X1 = pack_bf_trunc(e[8*cc+2], e[8*cc+3]);
                unsigned X2 = pack_bf_trunc(e[8*cc+4], e[8*cc+5]);
                unsigned X3 = pack_bf_trunc(e[8*cc+6], e[8*cc+7]);
                unsigned pX0 = __shfl_xor(X0, 32);
                unsigned pX1 = __shfl_xor(X1, 32);
                unsigned pX2 = __shfl_xor(X2, 32);
                unsigned pX3 = __shfl_xor(X3, 32);
                uvec4 t;
                t.x = lh ? pX2 : X0;
                t.y = lh ? pX3 : X1;
                t.z = lh ? X2  : pX0;
                t.w = lh ? X3  : pX1;
                short8 pf = __builtin_bit_cast(short8, t);
                int ks = 2 * kg + cc;
                int cp = ((2 * ks + lh) ^ (lr & 15)) * 8;
                short8 v0 = *(const short8*)&Vs[stage][lr * 128 + cp];
                short8 v1 = *(const short8*)&Vs[stage][(32 + lr) * 128 + cp];
                if (stage == 0) {
                    oh0 = __builtin_amdgcn_mfma_f32_32x32x16_bf16(v0, pf, oh0, 0, 0, 0);
                    oh1 = __builtin_amdgcn_mfma_f32_32x32x16_bf16(v1, pf, oh1, 0, 0, 0);
                } else {
                    ov0 = __builtin_amdgcn_mfma_f32_32x32x16_bf16(v0, pf, ov0, 0, 0, 0);
                    ov1 = __builtin_amdgcn_mfma_f32_32x32x16_bf16(v1, pf, ov1, 0, 0, 0);
                }
            }
        }
        float ssum = partial + __shfl_xor(partial, 32);
        if (stage == 0) ssA = ssum; else ssB = ssum;
    }

    __syncthreads();   // re-converge waves: adjacent 128B out-stores coalesce

    const float g  = gamma[0];
    const float g0 = g / ssA, g1 = g / ssB;
    const int xq = 32 * w + lr;
    #pragma unroll
    for (int reg = 0; reg < 16; reg++) {
        int ch = (reg & 3) + 8 * (reg >> 2) + 4 * lh;
        int idx0 = (bh * 64 + ch) * HW + y * 128 + xq;
        int idx1 = (bh * 64 + 32 + ch) * HW + y * 128 + xq;
        out[idx0] = g0 * oh0[reg] + g1 * ov0[reg] + xin[idx0];
        out[idx1] = g0 * oh1[reg] + g1 * ov1[reg] + xin[idx1];
    }
}

extern "C" void kernel_launch(void* const* d_in, const int* in_sizes, int n_in,
                              void* d_out, int out_size, void* d_ws, size_t ws_size,
                              hipStream_t stream) {
    const float* x     = (const float*)d_in[0];
    const float* Wq    = (const float*)d_in[1];
    const float* bq    = (const float*)d_in[2];
    const float* Wk    = (const float*)d_in[3];
    const float* bk    = (const float*)d_in[4];
    const float* Wv    = (const float*)d_in[5];
    const float* bv    = (const float*)d_in[6];
    const float* gamma = (const float*)d_in[7];
    float* out = (float*)d_out;

    unsigned short* Wb   = (unsigned short*)d_ws;
    unsigned short* qb16 = Wb + 320 * 256;
    unsigned short* kb16 = qb16 + 16 * HW * 8;
    unsigned short* qt16 = kb16 + 16 * HW * 8;
    unsigned short* kt16 = qt16 + 16 * HW * 8;
    unsigned short* vb16 = kt16 + 16 * HW * 8;
    unsigned short* vt16 = vb16 + 1024 * HW;
    // xt (bf16 x transposed) lives in d_out: consumed by proj before attn writes.
    unsigned short* xt = (unsigned short*)d_out;

    cast_xt_kernel<<<dim3(256, 4, 4), 256, 0, stream>>>(x, Wq, Wk, Wv, Wb, xt);
    proj_mfma_kernel<<<dim3(64, 5, 4), 256, 0, stream>>>(Wb, xt, bq, bk, bv, qb16, kb16, vb16);
    tqk_kernel<<<dim3(16, 32), 256, 0, stream>>>(qb16, kb16, qt16, kt16);
    tv_kernel<<<dim3(4, 1024), 256, 0, stream>>>(vb16, vt16);
    attn_kernel<<<dim3(128, 16), 256, 0, stream>>>(qb16, kb16, vb16, qt16, kt16, vt16, x, gamma, out);
}